// Round 12
// baseline (195.768 us; speedup 1.0000x reference)
//
#include <hip/hip_runtime.h>

// CrossAttention: conv1x1 over T (batched GEMM) -> per-head qkv (16x16) ->
// head-vs-head attention (64x64 per (c,t)) with exact entmax15 -> PV.
// v10: k_attn processes qt-tiles in PAIRS (2-way ILP on the serial
// entmax chain: shfl/sqrt/rcp latency of one tile hidden by the other's
// VALU ops). VGPR ~36->~56 (<=64 keeps 8 waves/SIMD). Same math per row.
// k_gemm v9 (128x256, BK=32, 48KiB dbuf, 2 blocks/CU), transpose/cvt as-is.
// ws: xT f16 [0,64Mi), X2 f16 [64Mi,128Mi). conv_w f16 scratch in d_out head.

typedef __attribute__((ext_vector_type(8))) _Float16 f16x8;
typedef __attribute__((ext_vector_type(4))) _Float16 f16x4;
typedef __attribute__((ext_vector_type(2))) _Float16 f16x2;
typedef __attribute__((ext_vector_type(4))) float f32x4;

union pk4 { f16x2 h2[2]; f16x4 h4; };

__device__ __forceinline__ f16x2 pkrtz(float a, float b){
  return __builtin_bit_cast(f16x2, __builtin_amdgcn_cvt_pkrtz(a, b));
}

__device__ __forceinline__ void gl_lds16(const void* g, void* l){
  __builtin_amdgcn_global_load_lds((const __attribute__((address_space(1))) void*)g,
                                   (__attribute__((address_space(3))) void*)l, 16, 0, 0);
}

#define ASM_BARRIER()  asm volatile("s_barrier" ::: "memory")
#define WAIT_LGKM0()   asm volatile("s_waitcnt lgkmcnt(0)" ::: "memory")
#define WAIT_VM3()     asm volatile("s_waitcnt vmcnt(3)" ::: "memory")
#define WAIT_VM0()     asm volatile("s_waitcnt vmcnt(0)" ::: "memory")

// ---------------- kernel 0: conv_w f32 -> f16 ----------------
__global__ __launch_bounds__(256) void k_cvt_w(const float* __restrict__ w,
                                               _Float16* __restrict__ wh){
  int i = (blockIdx.x * 256 + threadIdx.x) * 4;
  float4 v = *(const float4*)(w + i);
  f16x4 o = {(_Float16)v.x, (_Float16)v.y, (_Float16)v.z, (_Float16)v.w};
  *(f16x4*)(wh + i) = o;
}

// ------- kernel 1: x_en (c,t,e) f32 -> xT (c,e,t) f16 (64x64 LDS tiles) -------
__global__ __launch_bounds__(256) void k_transpose(const float* __restrict__ x,
                                                   _Float16* __restrict__ xT){
  __shared__ float tile[64][65];
  const int c  = blockIdx.z;
  const int t0 = blockIdx.y * 64;
  const int e0 = blockIdx.x * 64;
  const int tid = threadIdx.x;
  const int c4 = tid & 15;
  const int rb = tid >> 4;
  const float* src = x + ((size_t)c << 20) + (size_t)(t0 + rb) * 1024 + e0 + c4 * 4;
  #pragma unroll
  for (int p = 0; p < 4; ++p){
    float4 v = *(const float4*)(src + (size_t)p * 16 * 1024);
    tile[rb + p*16][c4*4+0] = v.x;
    tile[rb + p*16][c4*4+1] = v.y;
    tile[rb + p*16][c4*4+2] = v.z;
    tile[rb + p*16][c4*4+3] = v.w;
  }
  __syncthreads();
  _Float16* dst = xT + ((size_t)c << 20) + (size_t)(e0 + rb) * 1024 + t0 + c4 * 4;
  #pragma unroll
  for (int p = 0; p < 4; ++p){
    const int el = rb + p*16;
    f16x4 o = {(_Float16)tile[c4*4+0][el], (_Float16)tile[c4*4+1][el],
               (_Float16)tile[c4*4+2][el], (_Float16)tile[c4*4+3][el]};
    *(f16x4*)(dst + (size_t)p * 16 * 1024) = o;
  }
}

// ------- kernel 2: X2[c] = conv_w @ x[c] + conv_b (v9, unchanged) -------
__global__ __launch_bounds__(512, 2) void k_gemm(const _Float16* __restrict__ Aw,
                                                 const _Float16* __restrict__ BxT,
                                                 const float* __restrict__ bias,
                                                 _Float16* __restrict__ X2){
  __shared__ _Float16 smem[24576];   // 48 KiB: 2 x [A 8KiB | B 16KiB]
  char* ldsbase = (char*)smem;
  const int tid  = threadIdx.x;
  const int c    = blockIdx.z;
  const int brow = blockIdx.y;       // 0..7  (128-row o-tile)
  const int bcol = blockIdx.x;       // 0..3  (256-col e-tile)
  const int lane = tid & 63;
  const int wave = tid >> 6;
  const int wrow = wave >> 2;        // 0..1
  const int wcol = wave & 3;         // 0..3
  const int fr = lane & 15, fq = lane >> 4;
  const int fq16 = fq * 16;
  const int swz  = ((fr >> 1) & 3) << 4;

  const char* Ab8 = (const char*)(Aw  + (size_t)(brow*128) * 1024);
  const char* Bb8 = (const char*)(BxT + ((size_t)c << 20) + (size_t)(bcol*256) * 1024);

  const int srow = tid >> 2;
  const int scl  = ((tid & 3)*16) ^ (((srow >> 1) & 3) << 4);

#define STAGE(kt_, b_) do {                                                    \
    gl_lds16(Ab8 + (size_t)srow*2048 + (kt_)*64 + scl,                         \
             ldsbase + (b_)*24576 + tid*16);                                   \
    gl_lds16(Bb8 + (size_t)srow*2048 + (kt_)*64 + scl,                         \
             ldsbase + (b_)*24576 + 8192 + tid*16);                            \
    gl_lds16(Bb8 + (size_t)(128 + srow)*2048 + (kt_)*64 + scl,                 \
             ldsbase + (b_)*24576 + 16384 + tid*16);                           \
  } while(0)

  f32x4 acc[4][4];
  #pragma unroll
  for (int m = 0; m < 4; ++m)
    #pragma unroll
    for (int n = 0; n < 4; ++n)
      acc[m][n] = (f32x4){0.f, 0.f, 0.f, 0.f};

#define COMPUTE(b_) do {                                                       \
    const char* pA_ = ldsbase + (b_)*24576;                                    \
    const char* pB_ = pA_ + 8192;                                              \
    f16x8 aF[4], bF[4];                                                        \
    _Pragma("unroll")                                                          \
    for (int m = 0; m < 4; ++m)                                                \
      aF[m] = *(const f16x8*)(pA_ + (wrow*64 + m*16 + fr)*64 + (fq16 ^ swz));  \
    _Pragma("unroll")                                                          \
    for (int n = 0; n < 4; ++n)                                                \
      bF[n] = *(const f16x8*)(pB_ + (wcol*64 + n*16 + fr)*64 + (fq16 ^ swz));  \
    __builtin_amdgcn_s_setprio(1);                                             \
    _Pragma("unroll")                                                          \
    for (int m = 0; m < 4; ++m)                                                \
      _Pragma("unroll")                                                        \
      for (int n = 0; n < 4; ++n)                                              \
        acc[m][n] = __builtin_amdgcn_mfma_f32_16x16x32_f16(aF[m], bF[n],       \
                                                           acc[m][n],0,0,0);   \
    __builtin_amdgcn_s_setprio(0);                                             \
  } while(0)

  STAGE(0, 0);
  STAGE(1, 1);
  WAIT_VM3();
  ASM_BARRIER();

  #pragma unroll 2
  for (int kt = 0; kt < 32; ++kt){
    const int b = kt & 1;
    COMPUTE(b);
    if (kt < 31){
      WAIT_LGKM0();
      ASM_BARRIER();
      if (kt < 30){
        STAGE(kt + 2, b);
        WAIT_VM3();
      } else {
        WAIT_VM0();
      }
      ASM_BARRIER();
    }
  }

  _Float16* Cb = X2 + ((size_t)c << 20) + (size_t)(brow*128) * 1024 + bcol*256;
  const float* bb = bias + brow*128;
  #pragma unroll
  for (int m = 0; m < 4; ++m){
    #pragma unroll
    for (int r = 0; r < 4; ++r){
      const int orow = wrow*64 + m*16 + fq*4 + r;
      const float bv = bb[orow];
      #pragma unroll
      for (int n = 0; n < 4; ++n){
        const int ocol = wcol*64 + n*16 + fr;
        Cb[(size_t)orow * 1024 + ocol] = (_Float16)(acc[m][n][r] + bv);
      }
    }
  }
#undef STAGE
#undef COMPUTE
}

// ------- kernel 3: MFMA attention, qt-tiles processed in PAIRS. -------
// Fragment chain as v2-v9 (validated). Entmax per row: 16 vals/lane packed,
// 4-lane group reduce (shfl_xor 16,32), Newton x2 from closed-form init.
// Two independent qt chains live at once -> shfl/sqrt/rcp latency overlapped.
__global__ __launch_bounds__(256) void k_attn(const float* __restrict__ y_de,
                                              const _Float16* __restrict__ X2,
                                              const float* __restrict__ wq, const float* __restrict__ bq,
                                              const float* __restrict__ wk, const float* __restrict__ bk,
                                              const float* __restrict__ wv, const float* __restrict__ bv,
                                              float* __restrict__ out){
  const int tid  = threadIdx.x;
  const int wave = tid >> 6, lane = tid & 63;
  const size_t pair = (size_t)blockIdx.x * 4 + wave;
  const int l15 = lane & 15;
  const int g   = lane >> 4;

  f16x4 wqA, wkA, wvB;
  {
    float4 a = *(const float4*)(wq + l15*16 + g*4);
    float4 b = *(const float4*)(wk + l15*16 + g*4);
    float4 c = *(const float4*)(wv + l15*16 + g*4);
    wqA = (f16x4){(_Float16)a.x, (_Float16)a.y, (_Float16)a.z, (_Float16)a.w};
    wkA = (f16x4){(_Float16)b.x, (_Float16)b.y, (_Float16)b.z, (_Float16)b.w};
    wvB = (f16x4){(_Float16)c.x, (_Float16)c.y, (_Float16)c.z, (_Float16)c.w};
  }
  const float4 bqv = *(const float4*)(bq + g*4);
  const float4 bkv = *(const float4*)(bk + g*4);
  const float  bvv = bv[l15];

  const _Float16* xp = X2 + (pair << 10);
  f16x4 xF[4];
  #pragma unroll
  for (int kt = 0; kt < 4; ++kt)
    xF[kt] = *(const f16x4*)(xp + (kt*16 + l15)*16 + g*4);

  f16x4 kF[4], vF[4];
  #pragma unroll
  for (int kt = 0; kt < 4; ++kt){
    f32x4 t = __builtin_amdgcn_mfma_f32_16x16x16f16(wkA, xF[kt], (f32x4){0.f,0.f,0.f,0.f}, 0, 0, 0);
    kF[kt] = (f16x4){(_Float16)(t[0]+bkv.x), (_Float16)(t[1]+bkv.y),
                     (_Float16)(t[2]+bkv.z), (_Float16)(t[3]+bkv.w)};
    f32x4 s = __builtin_amdgcn_mfma_f32_16x16x16f16(xF[kt], wvB, (f32x4){0.f,0.f,0.f,0.f}, 0, 0, 0);
    vF[kt] = (f16x4){(_Float16)(s[0]+bvv), (_Float16)(s[1]+bvv),
                     (_Float16)(s[2]+bvv), (_Float16)(s[3]+bvv)};
  }

  const float* yp = y_de + (pair << 10);
  float* op = out + (pair << 10);

  const f16x2 ones = {(_Float16)1.f, (_Float16)1.f};
  const f16x2 zz   = {(_Float16)0.f, (_Float16)0.f};

  #pragma unroll
  for (int qp = 0; qp < 2; ++qp){
    const int qtA = qp*2, qtB = qp*2 + 1;

    // --- Q^T projections (fold 1/64) for both tiles ---
    float4 yvA = *(const float4*)(yp + (qtA*16 + l15)*16 + g*4);
    float4 yvB = *(const float4*)(yp + (qtB*16 + l15)*16 + g*4);
    f16x4 yFA = {(_Float16)yvA.x, (_Float16)yvA.y, (_Float16)yvA.z, (_Float16)yvA.w};
    f16x4 yFB = {(_Float16)yvB.x, (_Float16)yvB.y, (_Float16)yvB.z, (_Float16)yvB.w};
    f32x4 qA = __builtin_amdgcn_mfma_f32_16x16x16f16(wqA, yFA, (f32x4){0.f,0.f,0.f,0.f}, 0, 0, 0);
    f32x4 qB = __builtin_amdgcn_mfma_f32_16x16x16f16(wqA, yFB, (f32x4){0.f,0.f,0.f,0.f}, 0, 0, 0);
    f16x4 qFA = {(_Float16)((qA[0]+bqv.x)*0.015625f), (_Float16)((qA[1]+bqv.y)*0.015625f),
                 (_Float16)((qA[2]+bqv.z)*0.015625f), (_Float16)((qA[3]+bqv.w)*0.015625f)};
    f16x4 qFB = {(_Float16)((qB[0]+bqv.x)*0.015625f), (_Float16)((qB[1]+bqv.y)*0.015625f),
                 (_Float16)((qB[2]+bqv.z)*0.015625f), (_Float16)((qB[3]+bqv.w)*0.015625f)};

    // --- scores for both rows (8 MFMA, independent) ---
    f16x2 uA[8], uB[8];
    #pragma unroll
    for (int kt = 0; kt < 4; ++kt){
      f32x4 sA = __builtin_amdgcn_mfma_f32_16x16x16f16(kF[kt], qFA, (f32x4){0.f,0.f,0.f,0.f}, 0, 0, 0);
      f32x4 sB = __builtin_amdgcn_mfma_f32_16x16x16f16(kF[kt], qFB, (f32x4){0.f,0.f,0.f,0.f}, 0, 0, 0);
      uA[kt*2+0] = pkrtz(sA[0], sA[1]); uA[kt*2+1] = pkrtz(sA[2], sA[3]);
      uB[kt*2+0] = pkrtz(sB[0], sB[1]); uB[kt*2+1] = pkrtz(sB[2], sB[3]);
    }

    // --- row max (both) ---
    f16x2 mA0 = __builtin_elementwise_max(uA[0], uA[1]);
    f16x2 mB0 = __builtin_elementwise_max(uB[0], uB[1]);
    f16x2 mA1 = __builtin_elementwise_max(uA[2], uA[3]);
    f16x2 mB1 = __builtin_elementwise_max(uB[2], uB[3]);
    f16x2 mA2 = __builtin_elementwise_max(uA[4], uA[5]);
    f16x2 mB2 = __builtin_elementwise_max(uB[4], uB[5]);
    f16x2 mA3 = __builtin_elementwise_max(uA[6], uA[7]);
    f16x2 mB3 = __builtin_elementwise_max(uB[6], uB[7]);
    mA0 = __builtin_elementwise_max(mA0, mA1); mB0 = __builtin_elementwise_max(mB0, mB1);
    mA2 = __builtin_elementwise_max(mA2, mA3); mB2 = __builtin_elementwise_max(mB2, mB3);
    mA0 = __builtin_elementwise_max(mA0, mA2); mB0 = __builtin_elementwise_max(mB0, mB2);
    float mxA = fmaxf((float)mA0[0], (float)mA0[1]);
    float mxB = fmaxf((float)mB0[0], (float)mB0[1]);
    mxA = fmaxf(mxA, __shfl_xor(mxA, 16)); mxB = fmaxf(mxB, __shfl_xor(mxB, 16));
    mxA = fmaxf(mxA, __shfl_xor(mxA, 32)); mxB = fmaxf(mxB, __shfl_xor(mxB, 32));

    // --- closed-form full-support init (both) ---
    float S1Aa=0.f,S1Ab=0.f,S2Aa=0.f,S2Ab=0.f;
    float S1Ba=0.f,S1Bb=0.f,S2Ba=0.f,S2Bb=0.f;
    #pragma unroll
    for (int i = 0; i < 4; ++i){
      S1Aa = __builtin_amdgcn_fdot2(uA[i],   ones,    S1Aa, false);
      S1Ba = __builtin_amdgcn_fdot2(uB[i],   ones,    S1Ba, false);
      S1Ab = __builtin_amdgcn_fdot2(uA[i+4], ones,    S1Ab, false);
      S1Bb = __builtin_amdgcn_fdot2(uB[i+4], ones,    S1Bb, false);
      S2Aa = __builtin_amdgcn_fdot2(uA[i],   uA[i],   S2Aa, false);
      S2Ba = __builtin_amdgcn_fdot2(uB[i],   uB[i],   S2Ba, false);
      S2Ab = __builtin_amdgcn_fdot2(uA[i+4], uA[i+4], S2Ab, false);
      S2Bb = __builtin_amdgcn_fdot2(uB[i+4], uB[i+4], S2Bb, false);
    }
    float S1A = S1Aa + S1Ab, S2A = S2Aa + S2Ab;
    float S1B = S1Ba + S1Bb, S2B = S2Ba + S2Bb;
    S1A += __shfl_xor(S1A, 16); S1B += __shfl_xor(S1B, 16);
    S2A += __shfl_xor(S2A, 16); S2B += __shfl_xor(S2B, 16);
    S1A += __shfl_xor(S1A, 32); S1B += __shfl_xor(S1B, 32);
    S2A += __shfl_xor(S2A, 32); S2B += __shfl_xor(S2B, 32);
    const float meanA = S1A * 0.015625f, meanB = S1B * 0.015625f;
    const float ssA = S2A - S1A * meanA, ssB = S2B - S1B * meanB;
    float dA = fmaxf((1.0f - ssA) * 0.015625f, 0.0f);
    float dB = fmaxf((1.0f - ssB) * 0.015625f, 0.0f);
    float tauA = meanA - sqrtf(dA);
    float tauB = meanB - sqrtf(dB);
    tauA = fminf(tauA, mxA - 0.125f); tauB = fminf(tauB, mxB - 0.125f);
    tauA = fmaxf(tauA, mxA - 1.0f);   tauB = fmaxf(tauB, mxB - 1.0f);

    // --- Newton x2 (both chains interleaved) ---
    #pragma unroll
    for (int it = 0; it < 2; ++it){
      f16x2 ttA = pkrtz(tauA, tauA);
      f16x2 ttB = pkrtz(tauB, tauB);
      float T1Aa=0.f,T1Ab=0.f,T2Aa=0.f,T2Ab=0.f;
      float T1Ba=0.f,T1Bb=0.f,T2Ba=0.f,T2Bb=0.f;
      #pragma unroll
      for (int i = 0; i < 4; ++i){
        f16x2 rAa = __builtin_elementwise_max(uA[i]   - ttA, zz);
        f16x2 rBa = __builtin_elementwise_max(uB[i]   - ttB, zz);
        f16x2 rAb = __builtin_elementwise_max(uA[i+4] - ttA, zz);
        f16x2 rBb = __builtin_elementwise_max(uB[i+4] - ttB, zz);
        T1Aa = __builtin_amdgcn_fdot2(rAa, ones, T1Aa, false);
        T1Ba = __builtin_amdgcn_fdot2(rBa, ones, T1Ba, false);
        T1Ab = __builtin_amdgcn_fdot2(rAb, ones, T1Ab, false);
        T1Bb = __builtin_amdgcn_fdot2(rBb, ones, T1Bb, false);
        T2Aa = __builtin_amdgcn_fdot2(rAa, rAa, T2Aa, false);
        T2Ba = __builtin_amdgcn_fdot2(rBa, rBa, T2Ba, false);
        T2Ab = __builtin_amdgcn_fdot2(rAb, rAb, T2Ab, false);
        T2Bb = __builtin_amdgcn_fdot2(rBb, rBb, T2Bb, false);
      }
      float T1A = T1Aa + T1Ab, T2A = T2Aa + T2Ab;
      float T1B = T1Ba + T1Bb, T2B = T2Ba + T2Bb;
      T1A += __shfl_xor(T1A, 16); T1B += __shfl_xor(T1B, 16);
      T2A += __shfl_xor(T2A, 16); T2B += __shfl_xor(T2B, 16);
      T1A += __shfl_xor(T1A, 32); T1B += __shfl_xor(T1B, 32);
      T2A += __shfl_xor(T2A, 32); T2B += __shfl_xor(T2B, 32);
      tauA += (T2A - 1.0f) * __builtin_amdgcn_rcpf(2.0f * T1A);
      tauB += (T2B - 1.0f) * __builtin_amdgcn_rcpf(2.0f * T1B);
    }

    // --- p = clip(u - tau)^2 -> PV (both) ---
    const f16x2 ttA = pkrtz(tauA, tauA);
    const f16x2 ttB = pkrtz(tauB, tauB);
    f32x4 oA = (f32x4){0.f, 0.f, 0.f, 0.f};
    f32x4 oB = (f32x4){0.f, 0.f, 0.f, 0.f};
    #pragma unroll
    for (int kt = 0; kt < 4; ++kt){
      f16x2 rA0 = __builtin_elementwise_max(uA[kt*2+0] - ttA, zz);
      f16x2 rA1 = __builtin_elementwise_max(uA[kt*2+1] - ttA, zz);
      f16x2 rB0 = __builtin_elementwise_max(uB[kt*2+0] - ttB, zz);
      f16x2 rB1 = __builtin_elementwise_max(uB[kt*2+1] - ttB, zz);
      pk4 pA; pA.h2[0] = rA0 * rA0; pA.h2[1] = rA1 * rA1;
      pk4 pB; pB.h2[0] = rB0 * rB0; pB.h2[1] = rB1 * rB1;
      oA = __builtin_amdgcn_mfma_f32_16x16x16f16(pA.h4, vF[kt], oA, 0, 0, 0);
      oB = __builtin_amdgcn_mfma_f32_16x16x16f16(pB.h4, vF[kt], oB, 0, 0, 0);
    }

    #pragma unroll
    for (int r = 0; r < 4; ++r){
      op[(qtA*16 + g*4 + r)*16 + l15] = oA[r];
      op[(qtB*16 + g*4 + r)*16 + l15] = oB[r];
    }
  }
}

extern "C" void kernel_launch(void* const* d_in, const int* in_sizes, int n_in,
                              void* d_out, int out_size, void* d_ws, size_t ws_size,
                              hipStream_t stream) {
  (void)in_sizes; (void)n_in; (void)out_size; (void)ws_size;
  const float* x_en   = (const float*)d_in[0];
  const float* y_de   = (const float*)d_in[1];
  const float* wq     = (const float*)d_in[2];
  const float* bq     = (const float*)d_in[3];
  const float* wk     = (const float*)d_in[4];
  const float* bk     = (const float*)d_in[5];
  const float* wv     = (const float*)d_in[6];
  const float* bv     = (const float*)d_in[7];
  const float* conv_w = (const float*)d_in[8];
  const float* conv_b = (const float*)d_in[9];
  float* out = (float*)d_out;

  char* ws = (char*)d_ws;
  _Float16* xT = (_Float16*)ws;                        // 64 MiB f16 (c,e,t)
  _Float16* X2 = (_Float16*)(ws + (size_t)67108864);   // 64 MiB f16 (c,o,e)
  _Float16* wH = (_Float16*)d_out;                     // 2 MiB scratch (overwritten by k_attn)

  k_cvt_w    <<<dim3(1024),       dim3(256), 0, stream>>>(conv_w, wH);
  k_transpose<<<dim3(16, 16, 32), dim3(256), 0, stream>>>(x_en, xT);
  k_gemm     <<<dim3(4, 8, 32),   dim3(512), 0, stream>>>(wH, xT, conv_b, X2);
  k_attn     <<<dim3(8192),       dim3(256), 0, stream>>>(y_de, X2, wq, bq, wk, bk, wv, bv, out);
}

// Round 13
// 191.435 us; speedup vs baseline: 1.0226x; 1.0226x over previous
//
#include <hip/hip_runtime.h>

// CrossAttention: conv1x1 over T (batched GEMM) -> per-head qkv (16x16) ->
// head-vs-head attention (64x64 per (c,t)) with exact entmax15 -> PV.
// v11: k_gemm triple-buffered single-barrier K-loop (3x24KiB LDS = 72KiB,
// still 2 blocks/CU). Staging tile kt+2 targets a buffer whose last readers
// all passed the previous barrier -> the "done reading" barrier is gone:
// 1 barrier/K-tile (was 2) + 2-tile-deep prefetch. Counted vmcnt(3).
// k_attn reverted to v9 (unpaired; v10 pairing was neutral-to-negative).
// ws: xT f16 [0,64Mi), X2 f16 [64Mi,128Mi). conv_w f16 scratch in d_out head.

typedef __attribute__((ext_vector_type(8))) _Float16 f16x8;
typedef __attribute__((ext_vector_type(4))) _Float16 f16x4;
typedef __attribute__((ext_vector_type(2))) _Float16 f16x2;
typedef __attribute__((ext_vector_type(4))) float f32x4;

union pk4 { f16x2 h2[2]; f16x4 h4; };

__device__ __forceinline__ f16x2 pkrtz(float a, float b){
  return __builtin_bit_cast(f16x2, __builtin_amdgcn_cvt_pkrtz(a, b));
}

__device__ __forceinline__ void gl_lds16(const void* g, void* l){
  __builtin_amdgcn_global_load_lds((const __attribute__((address_space(1))) void*)g,
                                   (__attribute__((address_space(3))) void*)l, 16, 0, 0);
}

#define ASM_BARRIER()  asm volatile("s_barrier" ::: "memory")
#define WAIT_LGKM0()   asm volatile("s_waitcnt lgkmcnt(0)" ::: "memory")
#define WAIT_VM3()     asm volatile("s_waitcnt vmcnt(3)" ::: "memory")
#define WAIT_VM0()     asm volatile("s_waitcnt vmcnt(0)" ::: "memory")

// ---------------- kernel 0: conv_w f32 -> f16 ----------------
__global__ __launch_bounds__(256) void k_cvt_w(const float* __restrict__ w,
                                               _Float16* __restrict__ wh){
  int i = (blockIdx.x * 256 + threadIdx.x) * 4;
  float4 v = *(const float4*)(w + i);
  f16x4 o = {(_Float16)v.x, (_Float16)v.y, (_Float16)v.z, (_Float16)v.w};
  *(f16x4*)(wh + i) = o;
}

// ------- kernel 1: x_en (c,t,e) f32 -> xT (c,e,t) f16 (64x64 LDS tiles) -------
__global__ __launch_bounds__(256) void k_transpose(const float* __restrict__ x,
                                                   _Float16* __restrict__ xT){
  __shared__ float tile[64][65];
  const int c  = blockIdx.z;
  const int t0 = blockIdx.y * 64;
  const int e0 = blockIdx.x * 64;
  const int tid = threadIdx.x;
  const int c4 = tid & 15;
  const int rb = tid >> 4;
  const float* src = x + ((size_t)c << 20) + (size_t)(t0 + rb) * 1024 + e0 + c4 * 4;
  #pragma unroll
  for (int p = 0; p < 4; ++p){
    float4 v = *(const float4*)(src + (size_t)p * 16 * 1024);
    tile[rb + p*16][c4*4+0] = v.x;
    tile[rb + p*16][c4*4+1] = v.y;
    tile[rb + p*16][c4*4+2] = v.z;
    tile[rb + p*16][c4*4+3] = v.w;
  }
  __syncthreads();
  _Float16* dst = xT + ((size_t)c << 20) + (size_t)(e0 + rb) * 1024 + t0 + c4 * 4;
  #pragma unroll
  for (int p = 0; p < 4; ++p){
    const int el = rb + p*16;
    f16x4 o = {(_Float16)tile[c4*4+0][el], (_Float16)tile[c4*4+1][el],
               (_Float16)tile[c4*4+2][el], (_Float16)tile[c4*4+3][el]};
    *(f16x4*)(dst + (size_t)p * 16 * 1024) = o;
  }
}

// ------- kernel 2: X2[c] = conv_w @ x[c] + conv_b -------
// 128x256 tile, BK=32, 8 waves (2x4), per-wave out 64x64 (acc = 64 f32),
// TRIPLE-buffered LDS 72 KiB (3 x [A 8K | B 16K]) => 2 blocks/CU, ONE
// barrier per K-tile. Per iter: COMPUTE(bc); STAGE(kt+2 -> (bc+2)%3);
// lgkm0; vmcnt(3) [tile kt+1 landed, kt+2's stay in flight]; barrier.
// LDS rows 64B; bits-4..5 XOR swizzle both sides. STAGE dest lane-stride 16.
__global__ __launch_bounds__(512, 2) void k_gemm(const _Float16* __restrict__ Aw,
                                                 const _Float16* __restrict__ BxT,
                                                 const float* __restrict__ bias,
                                                 _Float16* __restrict__ X2){
  __shared__ _Float16 smem[36864];   // 72 KiB: 3 x [A 8KiB | B 16KiB]
  char* ldsbase = (char*)smem;
  const int tid  = threadIdx.x;
  const int c    = blockIdx.z;
  const int brow = blockIdx.y;       // 0..7  (128-row o-tile)
  const int bcol = blockIdx.x;       // 0..3  (256-col e-tile)
  const int lane = tid & 63;
  const int wave = tid >> 6;
  const int wrow = wave >> 2;        // 0..1
  const int wcol = wave & 3;         // 0..3
  const int fr = lane & 15, fq = lane >> 4;
  const int fq16 = fq * 16;
  const int swz  = ((fr >> 1) & 3) << 4;

  const char* Ab8 = (const char*)(Aw  + (size_t)(brow*128) * 1024);
  const char* Bb8 = (const char*)(BxT + ((size_t)c << 20) + (size_t)(bcol*256) * 1024);

  const int srow = tid >> 2;
  const int scl  = ((tid & 3)*16) ^ (((srow >> 1) & 3) << 4);

#define STAGE(kt_, b_) do {                                                    \
    gl_lds16(Ab8 + (size_t)srow*2048 + (kt_)*64 + scl,                         \
             ldsbase + (b_)*24576 + tid*16);                                   \
    gl_lds16(Bb8 + (size_t)srow*2048 + (kt_)*64 + scl,                         \
             ldsbase + (b_)*24576 + 8192 + tid*16);                            \
    gl_lds16(Bb8 + (size_t)(128 + srow)*2048 + (kt_)*64 + scl,                 \
             ldsbase + (b_)*24576 + 16384 + tid*16);                           \
  } while(0)

  f32x4 acc[4][4];
  #pragma unroll
  for (int m = 0; m < 4; ++m)
    #pragma unroll
    for (int n = 0; n < 4; ++n)
      acc[m][n] = (f32x4){0.f, 0.f, 0.f, 0.f};

#define COMPUTE(b_) do {                                                       \
    const char* pA_ = ldsbase + (b_)*24576;                                    \
    const char* pB_ = pA_ + 8192;                                              \
    f16x8 aF[4], bF[4];                                                        \
    _Pragma("unroll")                                                          \
    for (int m = 0; m < 4; ++m)                                                \
      aF[m] = *(const f16x8*)(pA_ + (wrow*64 + m*16 + fr)*64 + (fq16 ^ swz));  \
    _Pragma("unroll")                                                          \
    for (int n = 0; n < 4; ++n)                                                \
      bF[n] = *(const f16x8*)(pB_ + (wcol*64 + n*16 + fr)*64 + (fq16 ^ swz));  \
    __builtin_amdgcn_s_setprio(1);                                             \
    _Pragma("unroll")                                                          \
    for (int m = 0; m < 4; ++m)                                                \
      _Pragma("unroll")                                                        \
      for (int n = 0; n < 4; ++n)                                              \
        acc[m][n] = __builtin_amdgcn_mfma_f32_16x16x32_f16(aF[m], bF[n],       \
                                                           acc[m][n],0,0,0);   \
    __builtin_amdgcn_s_setprio(0);                                             \
  } while(0)

  // prologue: stage tiles 0,1 into bufs 0,1; wait tile0 (tile1 in flight)
  STAGE(0, 0);
  STAGE(1, 1);
  WAIT_VM3();
  ASM_BARRIER();

  int bc = 0;   // buffer of tile kt
  for (int kt = 0; kt < 32; ++kt){
    COMPUTE(bc);
    if (kt < 31){
      if (kt < 30){
        const int sb = (bc == 0) ? 2 : (bc - 1);   // (bc+2)%3
        STAGE(kt + 2, sb);                          // last read: compute(kt-1), pre-barrier
      }
      WAIT_LGKM0();                 // own ds_reads done (consumed by MFMAs)
      if (kt < 30) WAIT_VM3();      // tile kt+1 landed (kt+2's 3 in flight)
      else         WAIT_VM0();      // tail: tile 31 landed
      ASM_BARRIER();                // collective: next tile visible everywhere
    }
    bc = (bc == 2) ? 0 : bc + 1;
  }

  // epilogue: bias + f16 store
  _Float16* Cb = X2 + ((size_t)c << 20) + (size_t)(brow*128) * 1024 + bcol*256;
  const float* bb = bias + brow*128;
  #pragma unroll
  for (int m = 0; m < 4; ++m){
    #pragma unroll
    for (int r = 0; r < 4; ++r){
      const int orow = wrow*64 + m*16 + fq*4 + r;
      const float bv = bb[orow];
      #pragma unroll
      for (int n = 0; n < 4; ++n){
        const int ocol = wcol*64 + n*16 + fr;
        Cb[(size_t)orow * 1024 + ocol] = (_Float16)(acc[m][n][r] + bv);
      }
    }
  }
#undef STAGE
#undef COMPUTE
}

// ------- kernel 3: MFMA attention, packed-f16 entmax. wave = one (c,t) pair. -------
//   Kt = wk.X^T (D: K[kh=l15][d=g*4+r])  -> scores A-frag
//   Qt = wq.Y^T (D: Q[q =l15][d=g*4+r])  -> scores B-frag (x 1/64 folded)
//   V  = X.wv^T (D: V[kh=g*4+r][d=l15])  -> PV B-frag
//   S^T[kt] = mfma(Kt[kt], Qt)  (D: P[q=l15][kh=kt*16+g*4+r]) -> PV A-frag
// Entmax row q: 16 vals/lane as 8x f16x2; sums via v_dot2_f32_f16 (2x4 split
// chains); 4-lane group reduce (shfl_xor 16,32). Newton x2 from closed-form
// full-support init (exact for full support; quadratic convergence).
__global__ __launch_bounds__(256) void k_attn(const float* __restrict__ y_de,
                                              const _Float16* __restrict__ X2,
                                              const float* __restrict__ wq, const float* __restrict__ bq,
                                              const float* __restrict__ wk, const float* __restrict__ bk,
                                              const float* __restrict__ wv, const float* __restrict__ bv,
                                              float* __restrict__ out){
  const int tid  = threadIdx.x;
  const int wave = tid >> 6, lane = tid & 63;
  const size_t pair = (size_t)blockIdx.x * 4 + wave;
  const int l15 = lane & 15;
  const int g   = lane >> 4;

  f16x4 wqA, wkA, wvB;
  {
    float4 a = *(const float4*)(wq + l15*16 + g*4);
    float4 b = *(const float4*)(wk + l15*16 + g*4);
    float4 c = *(const float4*)(wv + l15*16 + g*4);
    wqA = (f16x4){(_Float16)a.x, (_Float16)a.y, (_Float16)a.z, (_Float16)a.w};
    wkA = (f16x4){(_Float16)b.x, (_Float16)b.y, (_Float16)b.z, (_Float16)b.w};
    wvB = (f16x4){(_Float16)c.x, (_Float16)c.y, (_Float16)c.z, (_Float16)c.w};
  }
  const float4 bqv = *(const float4*)(bq + g*4);
  const float4 bkv = *(const float4*)(bk + g*4);
  const float  bvv = bv[l15];

  const _Float16* xp = X2 + (pair << 10);
  f16x4 xF[4];
  #pragma unroll
  for (int kt = 0; kt < 4; ++kt)
    xF[kt] = *(const f16x4*)(xp + (kt*16 + l15)*16 + g*4);

  f16x4 kF[4], vF[4];
  #pragma unroll
  for (int kt = 0; kt < 4; ++kt){
    f32x4 t = __builtin_amdgcn_mfma_f32_16x16x16f16(wkA, xF[kt], (f32x4){0.f,0.f,0.f,0.f}, 0, 0, 0);
    kF[kt] = (f16x4){(_Float16)(t[0]+bkv.x), (_Float16)(t[1]+bkv.y),
                     (_Float16)(t[2]+bkv.z), (_Float16)(t[3]+bkv.w)};
    f32x4 s = __builtin_amdgcn_mfma_f32_16x16x16f16(xF[kt], wvB, (f32x4){0.f,0.f,0.f,0.f}, 0, 0, 0);
    vF[kt] = (f16x4){(_Float16)(s[0]+bvv), (_Float16)(s[1]+bvv),
                     (_Float16)(s[2]+bvv), (_Float16)(s[3]+bvv)};
  }

  const float* yp = y_de + (pair << 10);
  float* op = out + (pair << 10);

  const f16x2 ones = {(_Float16)1.f, (_Float16)1.f};
  const f16x2 zz   = {(_Float16)0.f, (_Float16)0.f};

  #pragma unroll
  for (int qt = 0; qt < 4; ++qt){
    // Q^T projection; fold 1/(2*sqrt(EMBED)) = 1/64
    float4 yv = *(const float4*)(yp + (qt*16 + l15)*16 + g*4);
    f16x4 yF = {(_Float16)yv.x, (_Float16)yv.y, (_Float16)yv.z, (_Float16)yv.w};
    f32x4 q = __builtin_amdgcn_mfma_f32_16x16x16f16(wqA, yF, (f32x4){0.f,0.f,0.f,0.f}, 0, 0, 0);
    f16x4 qF = {(_Float16)((q[0]+bqv.x)*0.015625f), (_Float16)((q[1]+bqv.y)*0.015625f),
                (_Float16)((q[2]+bqv.z)*0.015625f), (_Float16)((q[3]+bqv.w)*0.015625f)};

    // scores row q = qt*16+l15: 16 entries/lane as 8x packed f16
    f16x2 u8[8];
    #pragma unroll
    for (int kt = 0; kt < 4; ++kt){
      f32x4 s = __builtin_amdgcn_mfma_f32_16x16x16f16(kF[kt], qF, (f32x4){0.f,0.f,0.f,0.f}, 0, 0, 0);
      u8[kt*2+0] = pkrtz(s[0], s[1]);
      u8[kt*2+1] = pkrtz(s[2], s[3]);
    }

    // row max: packed tree + 4-lane group
    f16x2 m0 = __builtin_elementwise_max(u8[0], u8[1]);
    f16x2 m1 = __builtin_elementwise_max(u8[2], u8[3]);
    f16x2 m2 = __builtin_elementwise_max(u8[4], u8[5]);
    f16x2 m3 = __builtin_elementwise_max(u8[6], u8[7]);
    m0 = __builtin_elementwise_max(m0, m1);
    m2 = __builtin_elementwise_max(m2, m3);
    m0 = __builtin_elementwise_max(m0, m2);
    float mx = fmaxf((float)m0[0], (float)m0[1]);
    mx = fmaxf(mx, __shfl_xor(mx, 16));
    mx = fmaxf(mx, __shfl_xor(mx, 32));

    // closed-form full-support init (n=64), 2x split chains
    float S1a = 0.f, S1b = 0.f, S2a = 0.f, S2b = 0.f;
    #pragma unroll
    for (int i = 0; i < 4; ++i){
      S1a = __builtin_amdgcn_fdot2(u8[i],   ones,    S1a, false);
      S1b = __builtin_amdgcn_fdot2(u8[i+4], ones,    S1b, false);
      S2a = __builtin_amdgcn_fdot2(u8[i],   u8[i],   S2a, false);
      S2b = __builtin_amdgcn_fdot2(u8[i+4], u8[i+4], S2b, false);
    }
    float S1 = S1a + S1b, S2 = S2a + S2b;
    S1 += __shfl_xor(S1, 16); S2 += __shfl_xor(S2, 16);
    S1 += __shfl_xor(S1, 32); S2 += __shfl_xor(S2, 32);
    const float mean = S1 * 0.015625f;
    const float ss   = S2 - S1 * mean;          // sum (u-mean)^2
    float delta = fmaxf((1.0f - ss) * 0.015625f, 0.0f);
    float tau = mean - sqrtf(delta);
    tau = fminf(tau, mx - 0.125f);   // tau* <= mx - 1/8  (p_max >= 1/64)
    tau = fmaxf(tau, mx - 1.0f);     // tau* >= mx - 1

    // Newton on g(tau) = sum max(u-tau,0)^2 - 1, packed f16 + dot2, 2 iters
    #pragma unroll
    for (int it = 0; it < 2; ++it){
      f16x2 tt = pkrtz(tau, tau);
      float T1a = 0.f, T1b = 0.f, T2a = 0.f, T2b = 0.f;
      #pragma unroll
      for (int i = 0; i < 4; ++i){
        f16x2 ra = __builtin_elementwise_max(u8[i]   - tt, zz);
        f16x2 rb = __builtin_elementwise_max(u8[i+4] - tt, zz);
        T1a = __builtin_amdgcn_fdot2(ra, ones, T1a, false);
        T1b = __builtin_amdgcn_fdot2(rb, ones, T1b, false);
        T2a = __builtin_amdgcn_fdot2(ra, ra,   T2a, false);
        T2b = __builtin_amdgcn_fdot2(rb, rb,   T2b, false);
      }
      float T1 = T1a + T1b, T2 = T2a + T2b;
      T1 += __shfl_xor(T1, 16); T2 += __shfl_xor(T2, 16);
      T1 += __shfl_xor(T1, 32); T2 += __shfl_xor(T2, 32);
      tau += (T2 - 1.0f) * __builtin_amdgcn_rcpf(2.0f * T1);
    }

    // p = clip(u - tau)^2 packed -> PV A-fragments; PV MFMA
    const f16x2 tt = pkrtz(tau, tau);
    f32x4 o = (f32x4){0.f, 0.f, 0.f, 0.f};
    #pragma unroll
    for (int kt = 0; kt < 4; ++kt){
      f16x2 r0 = __builtin_elementwise_max(u8[kt*2+0] - tt, zz);
      f16x2 r1 = __builtin_elementwise_max(u8[kt*2+1] - tt, zz);
      pk4 pp; pp.h2[0] = r0 * r0; pp.h2[1] = r1 * r1;
      o = __builtin_amdgcn_mfma_f32_16x16x16f16(pp.h4, vF[kt], o, 0, 0, 0);
    }

    #pragma unroll
    for (int r = 0; r < 4; ++r)
      op[(qt*16 + g*4 + r)*16 + l15] = o[r];
  }
}

extern "C" void kernel_launch(void* const* d_in, const int* in_sizes, int n_in,
                              void* d_out, int out_size, void* d_ws, size_t ws_size,
                              hipStream_t stream) {
  (void)in_sizes; (void)n_in; (void)out_size; (void)ws_size;
  const float* x_en   = (const float*)d_in[0];
  const float* y_de   = (const float*)d_in[1];
  const float* wq     = (const float*)d_in[2];
  const float* bq     = (const float*)d_in[3];
  const float* wk     = (const float*)d_in[4];
  const float* bk     = (const float*)d_in[5];
  const float* wv     = (const float*)d_in[6];
  const float* bv     = (const float*)d_in[7];
  const float* conv_w = (const float*)d_in[8];
  const float* conv_b = (const float*)d_in[9];
  float* out = (float*)d_out;

  char* ws = (char*)d_ws;
  _Float16* xT = (_Float16*)ws;                        // 64 MiB f16 (c,e,t)
  _Float16* X2 = (_Float16*)(ws + (size_t)67108864);   // 64 MiB f16 (c,o,e)
  _Float16* wH = (_Float16*)d_out;                     // 2 MiB scratch (overwritten by k_attn)

  k_cvt_w    <<<dim3(1024),       dim3(256), 0, stream>>>(conv_w, wH);
  k_transpose<<<dim3(16, 16, 32), dim3(256), 0, stream>>>(x_en, xT);
  k_gemm     <<<dim3(4, 8, 32),   dim3(512), 0, stream>>>(wH, xT, conv_b, X2);
  k_attn     <<<dim3(8192),       dim3(256), 0, stream>>>(y_de, X2, wq, bq, wk, bk, wv, bv, out);
}

// Round 14
// 183.643 us; speedup vs baseline: 1.0660x; 1.0424x over previous
//
#include <hip/hip_runtime.h>

// CrossAttention: conv1x1 over T (batched GEMM) -> per-head qkv (16x16) ->
// head-vs-head attention (64x64 per (c,t)) with exact entmax15 -> PV.
// v12: k_gemm sync-amortization: BK 32->64, 16 waves, 256^2 tile, 128KiB
// dbuf. 16 K-tiles x 2 barriers = half the sync points of v8/v9/v11 (all
// ~80us, sync-overhead-bound: MFMA 38%, LDS ~35%, HBM 22% — nothing
// saturated). v4's verified bits-4..6 both-sides swizzle (128B rows),
// lane-stride-16 staging, counted vmcnt(4).
// k_attn = v9 exact (best measured), transpose/cvt unchanged.
// ws: xT f16 [0,64Mi), X2 f16 [64Mi,128Mi). conv_w f16 scratch in d_out head.

typedef __attribute__((ext_vector_type(8))) _Float16 f16x8;
typedef __attribute__((ext_vector_type(4))) _Float16 f16x4;
typedef __attribute__((ext_vector_type(2))) _Float16 f16x2;
typedef __attribute__((ext_vector_type(4))) float f32x4;

union pk4 { f16x2 h2[2]; f16x4 h4; };

__device__ __forceinline__ f16x2 pkrtz(float a, float b){
  return __builtin_bit_cast(f16x2, __builtin_amdgcn_cvt_pkrtz(a, b));
}

__device__ __forceinline__ void gl_lds16(const void* g, void* l){
  __builtin_amdgcn_global_load_lds((const __attribute__((address_space(1))) void*)g,
                                   (__attribute__((address_space(3))) void*)l, 16, 0, 0);
}

#define ASM_BARRIER()  asm volatile("s_barrier" ::: "memory")
#define WAIT_LGKM0()   asm volatile("s_waitcnt lgkmcnt(0)" ::: "memory")
#define WAIT_VM4()     asm volatile("s_waitcnt vmcnt(4)" ::: "memory")
#define WAIT_VM0()     asm volatile("s_waitcnt vmcnt(0)" ::: "memory")

// ---------------- kernel 0: conv_w f32 -> f16 ----------------
__global__ __launch_bounds__(256) void k_cvt_w(const float* __restrict__ w,
                                               _Float16* __restrict__ wh){
  int i = (blockIdx.x * 256 + threadIdx.x) * 4;
  float4 v = *(const float4*)(w + i);
  f16x4 o = {(_Float16)v.x, (_Float16)v.y, (_Float16)v.z, (_Float16)v.w};
  *(f16x4*)(wh + i) = o;
}

// ------- kernel 1: x_en (c,t,e) f32 -> xT (c,e,t) f16 (64x64 LDS tiles) -------
__global__ __launch_bounds__(256) void k_transpose(const float* __restrict__ x,
                                                   _Float16* __restrict__ xT){
  __shared__ float tile[64][65];
  const int c  = blockIdx.z;
  const int t0 = blockIdx.y * 64;
  const int e0 = blockIdx.x * 64;
  const int tid = threadIdx.x;
  const int c4 = tid & 15;
  const int rb = tid >> 4;
  const float* src = x + ((size_t)c << 20) + (size_t)(t0 + rb) * 1024 + e0 + c4 * 4;
  #pragma unroll
  for (int p = 0; p < 4; ++p){
    float4 v = *(const float4*)(src + (size_t)p * 16 * 1024);
    tile[rb + p*16][c4*4+0] = v.x;
    tile[rb + p*16][c4*4+1] = v.y;
    tile[rb + p*16][c4*4+2] = v.z;
    tile[rb + p*16][c4*4+3] = v.w;
  }
  __syncthreads();
  _Float16* dst = xT + ((size_t)c << 20) + (size_t)(e0 + rb) * 1024 + t0 + c4 * 4;
  #pragma unroll
  for (int p = 0; p < 4; ++p){
    const int el = rb + p*16;
    f16x4 o = {(_Float16)tile[c4*4+0][el], (_Float16)tile[c4*4+1][el],
               (_Float16)tile[c4*4+2][el], (_Float16)tile[c4*4+3][el]};
    *(f16x4*)(dst + (size_t)p * 16 * 1024) = o;
  }
}

// ------- kernel 2: X2[c] = conv_w @ x[c] + conv_b -------
// 256x256 tile, BK=64, 16 waves (4x4), per-wave out 64x64 (acc = 64 f32),
// dbuf LDS 128 KiB (2 x [A 32K | B 32K]). 16 K-tiles, 2 barriers each =
// half the sync points of BK=32 variants. Counted vmcnt(4) (never 0 until
// tail). 128B LDS rows; bits-4..6 XOR swizzle both sides (v4-verified).
// STAGE: chunk q=j*1024+tid -> dest q*16 (lane stride 16, m104 rule),
// row=q>>3, slot=q&7, source col pre-swizzled by ((row&7)<<4).
__global__ __launch_bounds__(1024) void k_gemm(const _Float16* __restrict__ Aw,
                                               const _Float16* __restrict__ BxT,
                                               const float* __restrict__ bias,
                                               _Float16* __restrict__ X2){
  __shared__ _Float16 smem[65536];   // 128 KiB: 2 x [A 32KiB | B 32KiB]
  char* ldsbase = (char*)smem;
  const int tid  = threadIdx.x;
  const int c    = blockIdx.z;
  const int brow = blockIdx.y;       // 0..3  (256-row o-tile)
  const int bcol = blockIdx.x;       // 0..3  (256-col e-tile)
  const int lane = tid & 63;
  const int wave = tid >> 6;
  const int wrow = wave >> 2;        // 0..3  (64-row group)
  const int wcol = wave & 3;         // 0..3  (64-col group)
  const int fr = lane & 15, fq = lane >> 4;
  const int fq16 = fq * 16;                  // byte k-offset within half-row
  const int swz  = (fr & 7) << 4;            // ds_read swizzle (bits 4-6)

  const char* Ab8 = (const char*)(Aw  + (size_t)(brow*256) * 1024);
  const char* Bb8 = (const char*)(BxT + ((size_t)c << 20) + (size_t)(bcol*256) * 1024);

#define STAGE(kt_, b_) do {                                                    \
    _Pragma("unroll")                                                          \
    for (int j = 0; j < 2; ++j){                                               \
      const int q_   = j*1024 + tid;                                           \
      const int row_ = q_ >> 3;                                                \
      const int cl_  = ((q_ & 7)*16) ^ ((row_ & 7) << 4);                      \
      gl_lds16(Ab8 + (size_t)row_*2048 + (kt_)*128 + cl_,                      \
               ldsbase + (b_)*65536 + q_*16);                                  \
      gl_lds16(Bb8 + (size_t)row_*2048 + (kt_)*128 + cl_,                      \
               ldsbase + (b_)*65536 + 32768 + q_*16);                          \
    }                                                                          \
  } while(0)

  f32x4 acc[4][4];
  #pragma unroll
  for (int m = 0; m < 4; ++m)
    #pragma unroll
    for (int n = 0; n < 4; ++n)
      acc[m][n] = (f32x4){0.f, 0.f, 0.f, 0.f};

#define COMPUTE(b_) do {                                                       \
    const char* pA_ = ldsbase + (b_)*65536;                                    \
    const char* pB_ = pA_ + 32768;                                             \
    _Pragma("unroll")                                                          \
    for (int ks = 0; ks < 2; ++ks){                                            \
      f16x8 aF[4], bF[4];                                                      \
      _Pragma("unroll")                                                        \
      for (int m = 0; m < 4; ++m)                                              \
        aF[m] = *(const f16x8*)(pA_ + (wrow*64 + m*16 + fr)*128                \
                                    + ((ks*64 + fq16) ^ swz));                 \
      _Pragma("unroll")                                                        \
      for (int n = 0; n < 4; ++n)                                              \
        bF[n] = *(const f16x8*)(pB_ + (wcol*64 + n*16 + fr)*128                \
                                    + ((ks*64 + fq16) ^ swz));                 \
      __builtin_amdgcn_s_setprio(1);                                           \
      _Pragma("unroll")                                                        \
      for (int m = 0; m < 4; ++m)                                              \
        _Pragma("unroll")                                                      \
        for (int n = 0; n < 4; ++n)                                            \
          acc[m][n] = __builtin_amdgcn_mfma_f32_16x16x32_f16(aF[m], bF[n],     \
                                                             acc[m][n],0,0,0); \
      __builtin_amdgcn_s_setprio(0);                                           \
    }                                                                          \
  } while(0)

  // prologue: stage K-tiles 0,1; wait tile0 (tile1's 4 stay in flight)
  STAGE(0, 0);
  STAGE(1, 1);
  WAIT_VM4();
  ASM_BARRIER();

  for (int kt = 0; kt < 16; ++kt){
    const int b = kt & 1;
    COMPUTE(b);
    if (kt < 15){
      WAIT_LGKM0();          // this wave done reading buf b
      ASM_BARRIER();         // all waves done reading buf b
      if (kt < 14){
        STAGE(kt + 2, b);    // overwrite buf b (safe after barrier)
        WAIT_VM4();          // kt+1's 4 loads landed (kt+2's in flight)
      } else {
        WAIT_VM0();          // last tile (15) fully landed
      }
      ASM_BARRIER();         // next-tile data visible to all waves
    }
  }

  // epilogue: bias + f16 store
  _Float16* Cb = X2 + ((size_t)c << 20) + (size_t)(brow*256) * 1024 + bcol*256;
  const float* bb = bias + brow*256;
  #pragma unroll
  for (int m = 0; m < 4; ++m){
    #pragma unroll
    for (int r = 0; r < 4; ++r){
      const int orow = wrow*64 + m*16 + fq*4 + r;
      const float bv = bb[orow];
      #pragma unroll
      for (int n = 0; n < 4; ++n){
        const int ocol = wcol*64 + n*16 + fr;
        Cb[(size_t)orow * 1024 + ocol] = (_Float16)(acc[m][n][r] + bv);
      }
    }
  }
#undef STAGE
#undef COMPUTE
}

// ------- kernel 3: MFMA attention, packed-f16 entmax. wave = one (c,t) pair. -------
//   Kt = wk.X^T (D: K[kh=l15][d=g*4+r])  -> scores A-frag
//   Qt = wq.Y^T (D: Q[q =l15][d=g*4+r])  -> scores B-frag (x 1/64 folded)
//   V  = X.wv^T (D: V[kh=g*4+r][d=l15])  -> PV B-frag
//   S^T[kt] = mfma(Kt[kt], Qt)  (D: P[q=l15][kh=kt*16+g*4+r]) -> PV A-frag
// Entmax row q: 16 vals/lane as 8x f16x2; sums via v_dot2_f32_f16 (2x4 split
// chains); 4-lane group reduce (shfl_xor 16,32). Newton x2 from closed-form
// full-support init (exact for full support; quadratic convergence).
__global__ __launch_bounds__(256) void k_attn(const float* __restrict__ y_de,
                                              const _Float16* __restrict__ X2,
                                              const float* __restrict__ wq, const float* __restrict__ bq,
                                              const float* __restrict__ wk, const float* __restrict__ bk,
                                              const float* __restrict__ wv, const float* __restrict__ bv,
                                              float* __restrict__ out){
  const int tid  = threadIdx.x;
  const int wave = tid >> 6, lane = tid & 63;
  const size_t pair = (size_t)blockIdx.x * 4 + wave;
  const int l15 = lane & 15;
  const int g   = lane >> 4;

  f16x4 wqA, wkA, wvB;
  {
    float4 a = *(const float4*)(wq + l15*16 + g*4);
    float4 b = *(const float4*)(wk + l15*16 + g*4);
    float4 c = *(const float4*)(wv + l15*16 + g*4);
    wqA = (f16x4){(_Float16)a.x, (_Float16)a.y, (_Float16)a.z, (_Float16)a.w};
    wkA = (f16x4){(_Float16)b.x, (_Float16)b.y, (_Float16)b.z, (_Float16)b.w};
    wvB = (f16x4){(_Float16)c.x, (_Float16)c.y, (_Float16)c.z, (_Float16)c.w};
  }
  const float4 bqv = *(const float4*)(bq + g*4);
  const float4 bkv = *(const float4*)(bk + g*4);
  const float  bvv = bv[l15];

  const _Float16* xp = X2 + (pair << 10);
  f16x4 xF[4];
  #pragma unroll
  for (int kt = 0; kt < 4; ++kt)
    xF[kt] = *(const f16x4*)(xp + (kt*16 + l15)*16 + g*4);

  f16x4 kF[4], vF[4];
  #pragma unroll
  for (int kt = 0; kt < 4; ++kt){
    f32x4 t = __builtin_amdgcn_mfma_f32_16x16x16f16(wkA, xF[kt], (f32x4){0.f,0.f,0.f,0.f}, 0, 0, 0);
    kF[kt] = (f16x4){(_Float16)(t[0]+bkv.x), (_Float16)(t[1]+bkv.y),
                     (_Float16)(t[2]+bkv.z), (_Float16)(t[3]+bkv.w)};
    f32x4 s = __builtin_amdgcn_mfma_f32_16x16x16f16(xF[kt], wvB, (f32x4){0.f,0.f,0.f,0.f}, 0, 0, 0);
    vF[kt] = (f16x4){(_Float16)(s[0]+bvv), (_Float16)(s[1]+bvv),
                     (_Float16)(s[2]+bvv), (_Float16)(s[3]+bvv)};
  }

  const float* yp = y_de + (pair << 10);
  float* op = out + (pair << 10);

  const f16x2 ones = {(_Float16)1.f, (_Float16)1.f};
  const f16x2 zz   = {(_Float16)0.f, (_Float16)0.f};

  #pragma unroll
  for (int qt = 0; qt < 4; ++qt){
    // Q^T projection; fold 1/(2*sqrt(EMBED)) = 1/64
    float4 yv = *(const float4*)(yp + (qt*16 + l15)*16 + g*4);
    f16x4 yF = {(_Float16)yv.x, (_Float16)yv.y, (_Float16)yv.z, (_Float16)yv.w};
    f32x4 q = __builtin_amdgcn_mfma_f32_16x16x16f16(wqA, yF, (f32x4){0.f,0.f,0.f,0.f}, 0, 0, 0);
    f16x4 qF = {(_Float16)((q[0]+bqv.x)*0.015625f), (_Float16)((q[1]+bqv.y)*0.015625f),
                (_Float16)((q[2]+bqv.z)*0.015625f), (_Float16)((q[3]+bqv.w)*0.015625f)};

    // scores row q = qt*16+l15: 16 entries/lane as 8x packed f16
    f16x2 u8[8];
    #pragma unroll
    for (int kt = 0; kt < 4; ++kt){
      f32x4 s = __builtin_amdgcn_mfma_f32_16x16x16f16(kF[kt], qF, (f32x4){0.f,0.f,0.f,0.f}, 0, 0, 0);
      u8[kt*2+0] = pkrtz(s[0], s[1]);
      u8[kt*2+1] = pkrtz(s[2], s[3]);
    }

    // row max: packed tree + 4-lane group
    f16x2 m0 = __builtin_elementwise_max(u8[0], u8[1]);
    f16x2 m1 = __builtin_elementwise_max(u8[2], u8[3]);
    f16x2 m2 = __builtin_elementwise_max(u8[4], u8[5]);
    f16x2 m3 = __builtin_elementwise_max(u8[6], u8[7]);
    m0 = __builtin_elementwise_max(m0, m1);
    m2 = __builtin_elementwise_max(m2, m3);
    m0 = __builtin_elementwise_max(m0, m2);
    float mx = fmaxf((float)m0[0], (float)m0[1]);
    mx = fmaxf(mx, __shfl_xor(mx, 16));
    mx = fmaxf(mx, __shfl_xor(mx, 32));

    // closed-form full-support init (n=64), 2x split chains
    float S1a = 0.f, S1b = 0.f, S2a = 0.f, S2b = 0.f;
    #pragma unroll
    for (int i = 0; i < 4; ++i){
      S1a = __builtin_amdgcn_fdot2(u8[i],   ones,    S1a, false);
      S1b = __builtin_amdgcn_fdot2(u8[i+4], ones,    S1b, false);
      S2a = __builtin_amdgcn_fdot2(u8[i],   u8[i],   S2a, false);
      S2b = __builtin_amdgcn_fdot2(u8[i+4], u8[i+4], S2b, false);
    }
    float S1 = S1a + S1b, S2 = S2a + S2b;
    S1 += __shfl_xor(S1, 16); S2 += __shfl_xor(S2, 16);
    S1 += __shfl_xor(S1, 32); S2 += __shfl_xor(S2, 32);
    const float mean = S1 * 0.015625f;
    const float ss   = S2 - S1 * mean;          // sum (u-mean)^2
    float delta = fmaxf((1.0f - ss) * 0.015625f, 0.0f);
    float tau = mean - sqrtf(delta);
    tau = fminf(tau, mx - 0.125f);   // tau* <= mx - 1/8  (p_max >= 1/64)
    tau = fmaxf(tau, mx - 1.0f);     // tau* >= mx - 1

    // Newton on g(tau) = sum max(u-tau,0)^2 - 1, packed f16 + dot2, 2 iters
    #pragma unroll
    for (int it = 0; it < 2; ++it){
      f16x2 tt = pkrtz(tau, tau);
      float T1a = 0.f, T1b = 0.f, T2a = 0.f, T2b = 0.f;
      #pragma unroll
      for (int i = 0; i < 4; ++i){
        f16x2 ra = __builtin_elementwise_max(u8[i]   - tt, zz);
        f16x2 rb = __builtin_elementwise_max(u8[i+4] - tt, zz);
        T1a = __builtin_amdgcn_fdot2(ra, ones, T1a, false);
        T1b = __builtin_amdgcn_fdot2(rb, ones, T1b, false);
        T2a = __builtin_amdgcn_fdot2(ra, ra,   T2a, false);
        T2b = __builtin_amdgcn_fdot2(rb, rb,   T2b, false);
      }
      float T1 = T1a + T1b, T2 = T2a + T2b;
      T1 += __shfl_xor(T1, 16); T2 += __shfl_xor(T2, 16);
      T1 += __shfl_xor(T1, 32); T2 += __shfl_xor(T2, 32);
      tau += (T2 - 1.0f) * __builtin_amdgcn_rcpf(2.0f * T1);
    }

    // p = clip(u - tau)^2 packed -> PV A-fragments; PV MFMA
    const f16x2 tt = pkrtz(tau, tau);
    f32x4 o = (f32x4){0.f, 0.f, 0.f, 0.f};
    #pragma unroll
    for (int kt = 0; kt < 4; ++kt){
      f16x2 r0 = __builtin_elementwise_max(u8[kt*2+0] - tt, zz);
      f16x2 r1 = __builtin_elementwise_max(u8[kt*2+1] - tt, zz);
      pk4 pp; pp.h2[0] = r0 * r0; pp.h2[1] = r1 * r1;
      o = __builtin_amdgcn_mfma_f32_16x16x16f16(pp.h4, vF[kt], o, 0, 0, 0);
    }

    #pragma unroll
    for (int r = 0; r < 4; ++r)
      op[(qt*16 + g*4 + r)*16 + l15] = o[r];
  }
}

extern "C" void kernel_launch(void* const* d_in, const int* in_sizes, int n_in,
                              void* d_out, int out_size, void* d_ws, size_t ws_size,
                              hipStream_t stream) {
  (void)in_sizes; (void)n_in; (void)out_size; (void)ws_size;
  const float* x_en   = (const float*)d_in[0];
  const float* y_de   = (const float*)d_in[1];
  const float* wq     = (const float*)d_in[2];
  const float* bq     = (const float*)d_in[3];
  const float* wk     = (const float*)d_in[4];
  const float* bk     = (const float*)d_in[5];
  const float* wv     = (const float*)d_in[6];
  const float* bv     = (const float*)d_in[7];
  const float* conv_w = (const float*)d_in[8];
  const float* conv_b = (const float*)d_in[9];
  float* out = (float*)d_out;

  char* ws = (char*)d_ws;
  _Float16* xT = (_Float16*)ws;                        // 64 MiB f16 (c,e,t)
  _Float16* X2 = (_Float16*)(ws + (size_t)67108864);   // 64 MiB f16 (c,o,e)
  _Float16* wH = (_Float16*)d_out;                     // 2 MiB scratch (overwritten by k_attn)

  k_cvt_w    <<<dim3(1024),       dim3(256),  0, stream>>>(conv_w, wH);
  k_transpose<<<dim3(16, 16, 32), dim3(256),  0, stream>>>(x_en, xT);
  k_gemm     <<<dim3(4, 4, 32),   dim3(1024), 0, stream>>>(wH, xT, conv_b, X2);
  k_attn     <<<dim3(8192),       dim3(256),  0, stream>>>(y_de, X2, wq, bq, wk, bk, wv, bv, out);
}